// Round 4
// baseline (232.267 us; speedup 1.0000x reference)
//
#include <hip/hip_runtime.h>
#include <hip/hip_bf16.h>
#include <hip/hip_cooperative_groups.h>

namespace cg = cooperative_groups;

// Problem constants (match reference)
#define BATCH 4096
#define NC    1024   // n_concepts (K)
#define NL    512    // n_lemmas   (N)
#define TSTEPS 50
#define GAMMA_C 0.95f
#define KAPPA_C 0.1f
#define FLOOR_C 1e-6f

typedef __attribute__((ext_vector_type(8))) short short8;  // 8 bf16 = 4 VGPRs
typedef __attribute__((ext_vector_type(4))) float f32x4;   // MFMA C/D frag

// ---------------- packed split fp32 -> bf16 hi + bf16 lo (RNE both) --------
__device__ __forceinline__ void split2_pk(float x0, float x1,
                                          unsigned& hp, unsigned& lp) {
    union { __hip_bfloat162 b; unsigned u; } ch, cl;
    ch.b = __float22bfloat162_rn(make_float2(x0, x1));
    hp = ch.u;
    const float hf0 = __uint_as_float(hp << 16);
    const float hf1 = __uint_as_float(hp & 0xFFFF0000u);
    cl.b = __float22bfloat162_rn(make_float2(x0 - hf0, x1 - hf1));
    lp = cl.u;
}

// ------- full-wave (64-lane) sum, broadcast to all lanes, via DPP ----------
__device__ __forceinline__ float wave_sum_bcast(float x) {
    float f = x;
    f += __int_as_float(__builtin_amdgcn_update_dpp(
            0, __float_as_int(f), 0x111, 0xf, 0xf, true));   // row_shr:1
    f += __int_as_float(__builtin_amdgcn_update_dpp(
            0, __float_as_int(f), 0x112, 0xf, 0xf, true));   // row_shr:2
    f += __int_as_float(__builtin_amdgcn_update_dpp(
            0, __float_as_int(f), 0x114, 0xf, 0xf, true));   // row_shr:4
    f += __int_as_float(__builtin_amdgcn_update_dpp(
            0, __float_as_int(f), 0x118, 0xf, 0xf, true));   // row_shr:8
    f += __int_as_float(__builtin_amdgcn_update_dpp(
            0, __float_as_int(f), 0x142, 0xa, 0xf, true));   // row_bcast:15
    f += __int_as_float(__builtin_amdgcn_update_dpp(
            0, __float_as_int(f), 0x143, 0xc, 0xf, true));   // row_bcast:31
    return __int_as_float(__builtin_amdgcn_readlane(__float_as_int(f), 63));
}

// global -> LDS DMA, 16 B per lane; HW dest = readfirstlane(lds) + lane*16
__device__ __forceinline__ void glds16(const unsigned short* g, unsigned short* l) {
    __builtin_amdgcn_global_load_lds(
        (__attribute__((address_space(1))) void*)(g),
        (__attribute__((address_space(3))) void*)(l), 16, 0, 0);
}

// ============================ FUSED (1 dispatch) ============================
// R3 post-mortem: three structurally different GEMMs all land at ~107 us
// total -> dispatch structure + fixed fill dominate, not GEMM internals.
// This kernel fuses convert -> GEMM -> recurrence via cooperative grid sync.
// 256 blocks (1/CU). splitK=1, TM=128, TN=64 (grid 32x8): D is final (8.4 MB,
// no partials). XCD swizzle pins the 8 blocks sharing an A m-panel to ONE XCD
// (mi = (l&7) + 8*(l>>6), ni = (l>>3)&7): phase 0 converts exactly the
// A-slice its XCD-mates read in phase 1 -> Ahi/Alo are XCD-L2 hits (2 MB/XCD)
// and W streams from L3 once per XCD (~34 MB total, vs 134 MB un-swizzled).
#define TM 128
#define TN 64
#define GK 32
#define FNST (NC / GK)   // 32 K-steps, full K per block

__global__ __launch_bounds__(256)
void fused_all(const float* __restrict__ A, const float* __restrict__ W,
               unsigned short* __restrict__ Whi, unsigned short* __restrict__ Wlo,
               unsigned short* __restrict__ Ahi, unsigned short* __restrict__ Alo,
               float* __restrict__ D,
               float* __restrict__ a_out, float* __restrict__ sel_out,
               float* __restrict__ conf_out) {
    // per buf (elems): Ah[128*32]=4096 @0, Al @4096, Bh[64*32]=2048 @8192,
    // Bl @10240 -> 12288 elems = 24 KB; x2 bufs = 48 KB
    __shared__ unsigned short S[2][12288];

    const int tid  = threadIdx.x;
    const int lane = tid & 63;
    const int w    = tid >> 6;
    const int l    = blockIdx.x;
    const int mi_b = (l & 7) + 8 * (l >> 6);   // 0..31, same-mi -> same XCD
    const int ni_b = (l >> 3) & 7;             // 0..7

    // ---------------- phase 0: convert W and A to bf16 hi/lo ----------------
    {
        // W: 2048 contiguous floats per block (256*2048 = 512*1024 exact)
        const size_t wofs = (size_t)l * 2048 + tid * 8;
        const float4 w0 = *(const float4*)(W + wofs);
        const float4 w1 = *(const float4*)(W + wofs + 4);
        uint4 h, lo;
        split2_pk(w0.x, w0.y, h.x, lo.x);
        split2_pk(w0.z, w0.w, h.y, lo.y);
        split2_pk(w1.x, w1.y, h.z, lo.z);
        split2_pk(w1.z, w1.w, h.w, lo.w);
        *(uint4*)(Whi + wofs) = h;
        *(uint4*)(Wlo + wofs) = lo;

        // A: rows [mi*128 + ni*16, +16) x full K (16*1024 floats, coalesced)
        const int r0A = mi_b * 128 + ni_b * 16;
        #pragma unroll
        for (int c = 0; c < 8; ++c) {
            const int row = r0A + c * 2 + (tid >> 7);
            const int col = (tid & 127) * 8;
            const size_t idx = (size_t)row * NC + col;
            const float4 a0 = *(const float4*)(A + idx);
            const float4 a1 = *(const float4*)(A + idx + 4);
            uint4 hh, ll;
            split2_pk(a0.x, a0.y, hh.x, ll.x);
            split2_pk(a0.z, a0.w, hh.y, ll.y);
            split2_pk(a1.x, a1.y, hh.z, ll.z);
            split2_pk(a1.z, a1.w, hh.w, ll.w);
            *(uint4*)(Ahi + idx) = hh;
            *(uint4*)(Alo + idx) = ll;
        }
    }
    __threadfence();
    cg::this_grid().sync();

    // ---------------- phase 1: GEMM (counted-vmcnt pipeline) ----------------
    const int m0 = mi_b * TM;
    const int n0 = ni_b * TN;

    // A staging: wave w rows [w*32,+32), 2 calls x 16 rows per array
    const unsigned short* gAh = Ahi + (size_t)(m0 + w * 32 + (lane >> 2)) * NC + (lane & 3) * 8;
    const unsigned short* gAl = Alo + (size_t)(m0 + w * 32 + (lane >> 2)) * NC + (lane & 3) * 8;
    // B staging: wave w rows [w*16,+16), 1 call per array
    const unsigned short* gBh = Whi + (size_t)(n0 + w * 16 + (lane >> 2)) * NC + (lane & 3) * 8;
    const unsigned short* gBl = Wlo + (size_t)(n0 + w * 16 + (lane >> 2)) * NC + (lane & 3) * 8;
    const int ald = w * 1024 + lane * 8;   // (w*32 rows)*GK + lane*8
    const int bld = w * 512  + lane * 8;   // (w*16 rows)*GK + lane*8

    const int sr   = lane & 15;
    const int quad = lane >> 4;
    const int mw = (w >> 1) * 64;          // wave-tile 64x32 (2M x 2N waves)
    const int nw = (w & 1) * 32;
    const int rA = (mw + sr) * GK + quad * 8;
    const int rB = (nw + sr) * GK + quad * 8;

    f32x4 acc[4][2];
    #pragma unroll
    for (int i = 0; i < 4; ++i)
        #pragma unroll
        for (int j = 0; j < 2; ++j)
            acc[i][j] = (f32x4){0.f, 0.f, 0.f, 0.f};

    // 6 glds16 per wave per stage -> vmcnt +6 per FSTAGE
    #define FSTAGE(buf, kofs)                                         \
        {                                                             \
            const int ko = (kofs);                                    \
            glds16(gAh + ko,           &S[buf][ald]);                 \
            glds16(gAh + ko + 16 * NC, &S[buf][ald + 512]);           \
            glds16(gAl + ko,           &S[buf][4096 + ald]);          \
            glds16(gAl + ko + 16 * NC, &S[buf][4096 + ald + 512]);    \
            glds16(gBh + ko,           &S[buf][8192 + bld]);          \
            glds16(gBl + ko,           &S[buf][10240 + bld]);         \
        }

    #define FKSTEP(CUR, VMSTR, DO_STAGE, NEXTK)                                \
        {                                                                      \
            asm volatile("s_waitcnt vmcnt(" VMSTR ")" ::: "memory");           \
            __builtin_amdgcn_sched_barrier(0);                                 \
            __builtin_amdgcn_s_barrier();                                      \
            __builtin_amdgcn_sched_barrier(0);                                 \
            short8 afh[4], afl[4], bfh[2], bfl[2];                             \
            _Pragma("unroll")                                                  \
            for (int mi = 0; mi < 4; ++mi) {                                   \
                afh[mi] = *(const short8*)&S[CUR][rA + mi * 512];              \
                afl[mi] = *(const short8*)&S[CUR][4096 + rA + mi * 512];       \
            }                                                                  \
            _Pragma("unroll")                                                  \
            for (int ni = 0; ni < 2; ++ni) {                                   \
                bfh[ni] = *(const short8*)&S[CUR][8192 + rB + ni * 512];       \
                bfl[ni] = *(const short8*)&S[CUR][10240 + rB + ni * 512];      \
            }                                                                  \
            _Pragma("unroll")                                                  \
            for (int mi = 0; mi < 4; ++mi) {                                   \
                _Pragma("unroll")                                              \
                for (int ni = 0; ni < 2; ++ni) {                               \
                    acc[mi][ni] = __builtin_amdgcn_mfma_f32_16x16x32_bf16(     \
                        afh[mi], bfh[ni], acc[mi][ni], 0, 0, 0);               \
                    acc[mi][ni] = __builtin_amdgcn_mfma_f32_16x16x32_bf16(     \
                        afh[mi], bfl[ni], acc[mi][ni], 0, 0, 0);               \
                    acc[mi][ni] = __builtin_amdgcn_mfma_f32_16x16x32_bf16(     \
                        afl[mi], bfh[ni], acc[mi][ni], 0, 0, 0);               \
                }                                                              \
            }                                                                  \
            __builtin_amdgcn_sched_barrier(0);                                 \
            __builtin_amdgcn_s_barrier();                                      \
            __builtin_amdgcn_sched_barrier(0);                                 \
            if (DO_STAGE) FSTAGE(CUR, NEXTK);                                  \
        }

    FSTAGE(0, 0);
    FSTAGE(1, GK);
    #pragma unroll 2
    for (int s = 0; s < FNST - 2; ++s)
        FKSTEP((s & 1), "6", true, (s + 2) * GK);
    FKSTEP(0, "6", false, 0);
    FKSTEP(1, "0", false, 0);

    // epilogue: C/D layout col = lane&15, row = quad*4 + reg  [m89/m91]
    #pragma unroll
    for (int mi2 = 0; mi2 < 4; ++mi2) {
        #pragma unroll
        for (int ni2 = 0; ni2 < 2; ++ni2) {
            const int col = n0 + nw + ni2 * 16 + sr;
            #pragma unroll
            for (int r = 0; r < 4; ++r) {
                const int row = m0 + mw + mi2 * 16 + quad * 4 + r;
                D[(size_t)row * NL + col] = acc[mi2][ni2][r];
            }
        }
    }
    __threadfence();
    cg::this_grid().sync();

    // ---------------- phase 2: 50-step recurrence + selection ---------------
    const int r0 = l * 16 + w * 4;      // 4 rows per wave
    float d[4][8];
    #pragma unroll
    for (int rr = 0; rr < 4; ++rr) {
        const float4 u0 = *(const float4*)(D + (size_t)(r0 + rr) * NL + lane * 8);
        const float4 u1 = *(const float4*)(D + (size_t)(r0 + rr) * NL + lane * 8 + 4);
        d[rr][0] = u0.x; d[rr][1] = u0.y; d[rr][2] = u0.z; d[rr][3] = u0.w;
        d[rr][4] = u1.x; d[rr][5] = u1.y; d[rr][6] = u1.z; d[rr][7] = u1.w;
    }

    float a[4][8];
    #pragma unroll
    for (int rr = 0; rr < 4; ++rr)
        #pragma unroll
        for (int j = 0; j < 8; ++j) a[rr][j] = 0.f;

    const float K1 = 1.0f + KAPPA_C;
    for (int t = 0; t < TSTEPS; ++t) {
        #pragma unroll
        for (int rr = 0; rr < 4; ++rr)
            #pragma unroll
            for (int j = 0; j < 8; ++j)
                a[rr][j] = fmaf(GAMMA_C, a[rr][j], d[rr][j]);

        float Sv[4];
        #pragma unroll
        for (int rr = 0; rr < 4; ++rr) {
            float t4a = a[rr][0] + a[rr][4], t4b = a[rr][1] + a[rr][5];
            float t4c = a[rr][2] + a[rr][6], t4d = a[rr][3] + a[rr][7];
            Sv[rr] = wave_sum_bcast((t4a + t4c) + (t4b + t4d));
        }
        #pragma unroll
        for (int rr = 0; rr < 4; ++rr) {
            const float h = -KAPPA_C * Sv[rr];
            #pragma unroll
            for (int j = 0; j < 8; ++j) {
                const float v = fmaf(K1, a[rr][j], h);
                a[rr][j] = v > 0.f ? v : 0.f;
            }
        }
    }

    #pragma unroll
    for (int rr = 0; rr < 4; ++rr) {
        const int row = r0 + rr;
        float m4a = fmaxf(a[rr][0], a[rr][4]), m4b = fmaxf(a[rr][1], a[rr][5]);
        float m4c = fmaxf(a[rr][2], a[rr][6]), m4d = fmaxf(a[rr][3], a[rr][7]);
        float peak = fmaxf(fmaxf(m4a, m4b), fmaxf(m4c, m4d));
        float s4a = a[rr][0] + a[rr][4], s4b = a[rr][1] + a[rr][5];
        float s4c = a[rr][2] + a[rr][6], s4d = a[rr][3] + a[rr][7];
        float ssum = wave_sum_bcast((s4a + s4b) + (s4c + s4d));

        #pragma unroll
        for (int m = 1; m < 64; m <<= 1)
            peak = fmaxf(peak, __shfl_xor(peak, m, 64));

        const float mean = ssum * (1.0f / (float)NL);
        const float conf = peak / fmaxf(mean, FLOOR_C);

        int idx = 0x7fffffff;
        #pragma unroll
        for (int j = 0; j < 8; ++j)
            if (a[rr][j] == peak) idx = min(idx, lane * 8 + j);
        #pragma unroll
        for (int m = 1; m < 64; m <<= 1)
            idx = min(idx, __shfl_xor(idx, m, 64));

        float4 o0, o1;
        o0.x = a[rr][0]; o0.y = a[rr][1]; o0.z = a[rr][2]; o0.w = a[rr][3];
        o1.x = a[rr][4]; o1.y = a[rr][5]; o1.z = a[rr][6]; o1.w = a[rr][7];
        float4* arp = (float4*)(a_out + (size_t)row * NL + lane * 8);
        arp[0] = o0; arp[1] = o1;

        if (lane == 0) {
            if (sel_out)  sel_out[row]  = (float)idx;
            if (conf_out) conf_out[row] = conf;
        }
    }
}

// ==================== FALLBACK: verified R3 3-kernel path ===================
#define W_FLOATS (NL * NC)
#define W_BLOCKS (W_FLOATS / (256 * 8))      // 256
#define A_BLOCKS ((BATCH * NC) / (256 * 8))  // 2048

__global__ __launch_bounds__(256)
void convert_hilo(const float* __restrict__ W, const float* __restrict__ A,
                  unsigned short* __restrict__ Whi, unsigned short* __restrict__ Wlo,
                  unsigned short* __restrict__ Ahi, unsigned short* __restrict__ Alo) {
    const int b = blockIdx.x;
    const float* src;
    unsigned short *dh, *dl;
    if (b < W_BLOCKS) {
        const size_t fidx = ((size_t)b * 256 + threadIdx.x) * 8;
        src = W + fidx; dh = Whi + fidx; dl = Wlo + fidx;
    } else {
        const size_t fidx = ((size_t)(b - W_BLOCKS) * 256 + threadIdx.x) * 8;
        src = A + fidx; dh = Ahi + fidx; dl = Alo + fidx;
    }
    const float4 v0 = ((const float4*)src)[0];
    const float4 v1 = ((const float4*)src)[1];
    uint4 h, l;
    split2_pk(v0.x, v0.y, h.x, l.x);
    split2_pk(v0.z, v0.w, h.y, l.y);
    split2_pk(v1.x, v1.y, h.z, l.z);
    split2_pk(v1.z, v1.w, h.w, l.w);
    *(uint4*)dh = h;
    *(uint4*)dl = l;
}

#define TM3 128
#define TN3 128
#define SPLITK 2
#define NST3 (NC / SPLITK / GK)   // 16

__global__ __launch_bounds__(256)
void gemm_bf16x2(const unsigned short* __restrict__ Ahi, const unsigned short* __restrict__ Alo,
                 const unsigned short* __restrict__ Whi, const unsigned short* __restrict__ Wlo,
                 float* __restrict__ Dp) {
    __shared__ unsigned short S[2][4][TM3 * GK];

    const int tid  = threadIdx.x;
    const int lane = tid & 63;
    const int w    = tid >> 6;
    const int m0 = blockIdx.x * TM3;
    const int n0 = blockIdx.y * TN3;
    const int kb = blockIdx.z * (NC / SPLITK);

    const int srow = w * 32 + (lane >> 2);
    const int scol = (lane & 3) * 8;
    const unsigned short* gAh = Ahi + (size_t)(m0 + srow) * NC + kb + scol;
    const unsigned short* gAl = Alo + (size_t)(m0 + srow) * NC + kb + scol;
    const unsigned short* gBh = Whi + (size_t)(n0 + srow) * NC + kb + scol;
    const unsigned short* gBl = Wlo + (size_t)(n0 + srow) * NC + kb + scol;
    const int ld0 = (w * 32) * GK + lane * 8;

    const int mw   = (w >> 1) * 64;
    const int nw   = (w & 1) * 64;
    const int sr   = lane & 15;
    const int quad = lane >> 4;
    const int rA = (mw + sr) * GK + quad * 8;
    const int rB = (nw + sr) * GK + quad * 8;

    f32x4 acc[4][4];
    #pragma unroll
    for (int i = 0; i < 4; ++i)
        #pragma unroll
        for (int j = 0; j < 4; ++j)
            acc[i][j] = (f32x4){0.f, 0.f, 0.f, 0.f};

    #define STAGE3(buf, kofs)                                         \
        {                                                             \
            const int ko = (kofs);                                    \
            glds16(gAh + ko,           &S[buf][0][ld0]);              \
            glds16(gAh + ko + 16 * NC, &S[buf][0][ld0 + 16 * GK]);    \
            glds16(gAl + ko,           &S[buf][1][ld0]);              \
            glds16(gAl + ko + 16 * NC, &S[buf][1][ld0 + 16 * GK]);    \
            glds16(gBh + ko,           &S[buf][2][ld0]);              \
            glds16(gBh + ko + 16 * NC, &S[buf][2][ld0 + 16 * GK]);    \
            glds16(gBl + ko,           &S[buf][3][ld0]);              \
            glds16(gBl + ko + 16 * NC, &S[buf][3][ld0 + 16 * GK]);    \
        }

    #define KSTEP3(CUR, VMSTR, DO_STAGE, NEXTK)                                \
        {                                                                      \
            asm volatile("s_waitcnt vmcnt(" VMSTR ")" ::: "memory");           \
            __builtin_amdgcn_sched_barrier(0);                                 \
            __builtin_amdgcn_s_barrier();                                      \
            __builtin_amdgcn_sched_barrier(0);                                 \
            short8 afh[4], afl[4], bfh[4], bfl[4];                             \
            _Pragma("unroll")                                                  \
            for (int mi = 0; mi < 4; ++mi) {                                   \
                afh[mi] = *(const short8*)&S[CUR][0][rA + mi * 16 * GK];       \
                afl[mi] = *(const short8*)&S[CUR][1][rA + mi * 16 * GK];       \
            }                                                                  \
            _Pragma("unroll")                                                  \
            for (int ni = 0; ni < 4; ++ni) {                                   \
                bfh[ni] = *(const short8*)&S[CUR][2][rB + ni * 16 * GK];       \
                bfl[ni] = *(const short8*)&S[CUR][3][rB + ni * 16 * GK];       \
            }                                                                  \
            _Pragma("unroll")                                                  \
            for (int mi = 0; mi < 4; ++mi) {                                   \
                _Pragma("unroll")                                              \
                for (int ni = 0; ni < 4; ++ni) {                               \
                    acc[mi][ni] = __builtin_amdgcn_mfma_f32_16x16x32_bf16(     \
                        afh[mi], bfh[ni], acc[mi][ni], 0, 0, 0);               \
                    acc[mi][ni] = __builtin_amdgcn_mfma_f32_16x16x32_bf16(     \
                        afh[mi], bfl[ni], acc[mi][ni], 0, 0, 0);               \
                    acc[mi][ni] = __builtin_amdgcn_mfma_f32_16x16x32_bf16(     \
                        afl[mi], bfh[ni], acc[mi][ni], 0, 0, 0);               \
                }                                                              \
            }                                                                  \
            __builtin_amdgcn_sched_barrier(0);                                 \
            __builtin_amdgcn_s_barrier();                                      \
            __builtin_amdgcn_sched_barrier(0);                                 \
            if (DO_STAGE) STAGE3(CUR, NEXTK);                                  \
        }

    STAGE3(0, 0);
    STAGE3(1, GK);
    #pragma unroll 2
    for (int s = 0; s < NST3 - 2; ++s)
        KSTEP3((s & 1), "8", true, (s + 2) * GK);
    KSTEP3(0, "8", false, 0);
    KSTEP3(1, "0", false, 0);

    float* Dz = Dp + (size_t)blockIdx.z * BATCH * NL;
    #pragma unroll
    for (int mi = 0; mi < 4; ++mi) {
        #pragma unroll
        for (int ni = 0; ni < 4; ++ni) {
            const int col = n0 + nw + ni * 16 + sr;
            #pragma unroll
            for (int r = 0; r < 4; ++r) {
                const int row = m0 + mw + mi * 16 + quad * 4 + r;
                Dz[(size_t)row * NL + col] = acc[mi][ni][r];
            }
        }
    }
}

template<int SK>
__global__ __launch_bounds__(256)
void iterate_select(const float* __restrict__ Dp,
                    float* __restrict__ a_out,
                    float* __restrict__ sel_out, float* __restrict__ conf_out) {
    const int lane = threadIdx.x & 63;
    const int wave = threadIdx.x >> 6;
    const int row  = blockIdx.x * 4 + wave;

    float d[8];
    {
        float4 v[SK][2];
        #pragma unroll
        for (int s = 0; s < SK; ++s) {
            const float4* ps = (const float4*)(Dp + (size_t)s * BATCH * NL
                                               + (size_t)row * NL + lane * 8);
            v[s][0] = ps[0];
            v[s][1] = ps[1];
        }
        d[0] = v[0][0].x; d[1] = v[0][0].y; d[2] = v[0][0].z; d[3] = v[0][0].w;
        d[4] = v[0][1].x; d[5] = v[0][1].y; d[6] = v[0][1].z; d[7] = v[0][1].w;
        #pragma unroll
        for (int s = 1; s < SK; ++s) {
            d[0] += v[s][0].x; d[1] += v[s][0].y; d[2] += v[s][0].z; d[3] += v[s][0].w;
            d[4] += v[s][1].x; d[5] += v[s][1].y; d[6] += v[s][1].z; d[7] += v[s][1].w;
        }
    }

    float a[8];
    #pragma unroll
    for (int j = 0; j < 8; ++j) a[j] = 0.f;
    const float K1 = 1.0f + KAPPA_C;

    for (int t = 0; t < TSTEPS; ++t) {
        #pragma unroll
        for (int j = 0; j < 8; ++j) a[j] = fmaf(GAMMA_C, a[j], d[j]);
        float t4a = a[0] + a[4], t4b = a[1] + a[5], t4c = a[2] + a[6], t4d = a[3] + a[7];
        const float S = wave_sum_bcast((t4a + t4c) + (t4b + t4d));
        const float h = -KAPPA_C * S;
        #pragma unroll
        for (int j = 0; j < 8; ++j) {
            const float v = fmaf(K1, a[j], h);
            a[j] = v > 0.f ? v : 0.f;
        }
    }

    float m4a = fmaxf(a[0], a[4]), m4b = fmaxf(a[1], a[5]);
    float m4c = fmaxf(a[2], a[6]), m4d = fmaxf(a[3], a[7]);
    float peak = fmaxf(fmaxf(m4a, m4b), fmaxf(m4c, m4d));
    float s4a = a[0] + a[4], s4b = a[1] + a[5], s4c = a[2] + a[6], s4d = a[3] + a[7];
    float ssum = wave_sum_bcast((s4a + s4b) + (s4c + s4d));

    #pragma unroll
    for (int m = 1; m < 64; m <<= 1)
        peak = fmaxf(peak, __shfl_xor(peak, m, 64));

    const float mean = ssum * (1.0f / (float)NL);
    const float conf = peak / fmaxf(mean, FLOOR_C);

    int idx = 0x7fffffff;
    #pragma unroll
    for (int j = 0; j < 8; ++j)
        if (a[j] == peak) idx = min(idx, lane * 8 + j);
    #pragma unroll
    for (int m = 1; m < 64; m <<= 1)
        idx = min(idx, __shfl_xor(idx, m, 64));

    float4* ar = (float4*)(a_out + (size_t)row * NL + lane * 8);
    float4 o0, o1;
    o0.x = a[0]; o0.y = a[1]; o0.z = a[2]; o0.w = a[3];
    o1.x = a[4]; o1.y = a[5]; o1.z = a[6]; o1.w = a[7];
    ar[0] = o0; ar[1] = o1;

    if (lane == 0) {
        if (sel_out)  sel_out[row]  = (float)idx;
        if (conf_out) conf_out[row] = conf;
    }
}

extern "C" void kernel_launch(void* const* d_in, const int* in_sizes, int n_in,
                              void* d_out, int out_size, void* d_ws, size_t ws_size,
                              hipStream_t stream) {
    const float* c_lex = (const float*)d_in[0];
    const float* W     = (const float*)d_in[1];
    // d_in[2] = a0 (zeros at every reset; recurrence inits a=0 directly)

    // workspace: D (room for 2 partials, fallback) + Whi/Wlo + Ahi/Alo
    float* D = (float*)d_ws;
    unsigned short* Whi = (unsigned short*)(D + 2ull * BATCH * NL);
    unsigned short* Wlo = Whi + (size_t)NL * NC;
    unsigned short* Ahi = Wlo + (size_t)NL * NC;
    unsigned short* Alo = Ahi + (size_t)BATCH * NC;

    float* a_out = (float*)d_out;
    float* sel   = nullptr;
    float* conf  = nullptr;
    const int base = BATCH * NL;
    if (out_size >= base + 2 * BATCH) {        // (a, selected, confidence)
        sel  = a_out + base;
        conf = a_out + base + BATCH;
    } else if (out_size >= base + BATCH) {     // (a, confidence)
        conf = a_out + base;
    }

    void* args[] = {(void*)&c_lex, (void*)&W, (void*)&Whi, (void*)&Wlo,
                    (void*)&Ahi, (void*)&Alo, (void*)&D,
                    (void*)&a_out, (void*)&sel, (void*)&conf};
    hipError_t e = hipLaunchCooperativeKernel((const void*)fused_all,
                                              dim3(256), dim3(256),
                                              args, 0, stream);
    if (e != hipSuccess) {
        // fallback: verified 3-kernel pipeline (R3)
        convert_hilo<<<dim3(W_BLOCKS + A_BLOCKS), 256, 0, stream>>>(
            W, c_lex, Whi, Wlo, Ahi, Alo);
        gemm_bf16x2<<<dim3(BATCH / TM3, NL / TN3, SPLITK), 256, 0, stream>>>(
            Ahi, Alo, Whi, Wlo, D);
        iterate_select<SPLITK><<<dim3(BATCH / 4), 256, 0, stream>>>(
            D, a_out, sel, conf);
    }
}

// Round 5
// 107.700 us; speedup vs baseline: 2.1566x; 2.1566x over previous
//
#include <hip/hip_runtime.h>
#include <hip/hip_bf16.h>

// Problem constants (match reference)
#define BATCH 4096
#define NC    1024   // n_concepts (K)
#define NL    512    // n_lemmas   (N)
#define TSTEPS 50
#define GAMMA_C 0.95f
#define KAPPA_C 0.1f
#define FLOOR_C 1e-6f

typedef __attribute__((ext_vector_type(8))) short short8;  // 8 bf16 = 4 VGPRs
typedef __attribute__((ext_vector_type(4))) float f32x4;   // MFMA C/D frag

// ---------------- packed split fp32 -> bf16 hi + bf16 lo (RNE both) --------
__device__ __forceinline__ void split2_pk(float x0, float x1,
                                          unsigned& hp, unsigned& lp) {
    union { __hip_bfloat162 b; unsigned u; } ch, cl;
    ch.b = __float22bfloat162_rn(make_float2(x0, x1));
    hp = ch.u;
    const float hf0 = __uint_as_float(hp << 16);
    const float hf1 = __uint_as_float(hp & 0xFFFF0000u);
    cl.b = __float22bfloat162_rn(make_float2(x0 - hf0, x1 - hf1));
    lp = cl.u;
}

// ---- convert BOTH W and A (c_lex) fp32 -> bf16 hi/lo, 8 floats/thread -----
#define W_FLOATS (NL * NC)                   // 524288
#define W_BLOCKS (W_FLOATS / (256 * 8))      // 256
#define A_BLOCKS ((BATCH * NC) / (256 * 8))  // 2048

__global__ __launch_bounds__(256)
void convert_hilo(const float* __restrict__ W, const float* __restrict__ A,
                  unsigned short* __restrict__ Whi, unsigned short* __restrict__ Wlo,
                  unsigned short* __restrict__ Ahi, unsigned short* __restrict__ Alo) {
    const int b = blockIdx.x;
    const float* src;
    unsigned short *dh, *dl;
    if (b < W_BLOCKS) {
        const size_t fidx = ((size_t)b * 256 + threadIdx.x) * 8;
        src = W + fidx; dh = Whi + fidx; dl = Wlo + fidx;
    } else {
        const size_t fidx = ((size_t)(b - W_BLOCKS) * 256 + threadIdx.x) * 8;
        src = A + fidx; dh = Ahi + fidx; dl = Alo + fidx;
    }
    const float4 v0 = ((const float4*)src)[0];
    const float4 v1 = ((const float4*)src)[1];
    uint4 h, l;
    split2_pk(v0.x, v0.y, h.x, l.x);
    split2_pk(v0.z, v0.w, h.y, l.y);
    split2_pk(v1.x, v1.y, h.z, l.z);
    split2_pk(v1.z, v1.w, h.w, l.w);
    *(uint4*)dh = h;
    *(uint4*)dl = l;
}

// ------- full-wave (64-lane) sum, broadcast to all lanes, via DPP ----------
__device__ __forceinline__ float wave_sum_bcast(float x) {
    float f = x;
    f += __int_as_float(__builtin_amdgcn_update_dpp(
            0, __float_as_int(f), 0x111, 0xf, 0xf, true));   // row_shr:1
    f += __int_as_float(__builtin_amdgcn_update_dpp(
            0, __float_as_int(f), 0x112, 0xf, 0xf, true));   // row_shr:2
    f += __int_as_float(__builtin_amdgcn_update_dpp(
            0, __float_as_int(f), 0x114, 0xf, 0xf, true));   // row_shr:4
    f += __int_as_float(__builtin_amdgcn_update_dpp(
            0, __float_as_int(f), 0x118, 0xf, 0xf, true));   // row_shr:8
    f += __int_as_float(__builtin_amdgcn_update_dpp(
            0, __float_as_int(f), 0x142, 0xa, 0xf, true));   // row_bcast:15
    f += __int_as_float(__builtin_amdgcn_update_dpp(
            0, __float_as_int(f), 0x143, 0xc, 0xf, true));   // row_bcast:31
    return __int_as_float(__builtin_amdgcn_readlane(__float_as_int(f), 63));
}

// global -> LDS DMA, 16 B per lane; HW dest = readfirstlane(lds) + lane*16
__device__ __forceinline__ void glds16(const unsigned short* g, unsigned short* l) {
    __builtin_amdgcn_global_load_lds(
        (__attribute__((address_space(1))) void*)(g),
        (__attribute__((address_space(3))) void*)(l), 16, 0, 0);
}

// ------------- MFMA GEMM: D = Ahi*Whi^T + Ahi*Wlo^T + Alo*Whi^T -------------
// R4 post-mortem: R3 ran 256 blocks = 1 wave/SIMD (stalls fully exposed) and
// no XCD locality (~270 MB L3 traffic: A pulled 4x, W 32x). Fix:
//  (1) splitK=4 -> 512 blocks = 2 blocks/CU = 2 waves/SIMD (R0/R1 occupancy)
//      while keeping R3's counted-vmcnt pipeline (vmcnt(8) steady, 0 only at
//      the tail).
//  (2) XCD-aware relabel (b%8 = XCD round-robin assumption, m09): the 16
//      blocks sharing an A m-panel all land on one XCD -> panel is pulled
//      into that XCD's L2 once (2 MB/XCD). L3 traffic ~270 -> ~70 MB.
#define TM 128
#define TN 128
#define GK 32
#define SPLITK 4
#define NST (NC / SPLITK / GK)   // 8

__global__ __launch_bounds__(256)
void gemm_bf16x2(const unsigned short* __restrict__ Ahi, const unsigned short* __restrict__ Alo,
                 const unsigned short* __restrict__ Whi, const unsigned short* __restrict__ Wlo,
                 float* __restrict__ Dp) {
    // 2 buffers x 4 arrays (AsH, AsL, BsH, BsL) x [128][32] bf16 = 64 KB
    __shared__ unsigned short S[2][4][TM * GK];

    const int tid  = threadIdx.x;
    const int lane = tid & 63;
    const int w    = tid >> 6;

    // XCD-aware relabel: b -> (mi, ni, kz) with all 16 blocks of an A-panel
    // (same mi) on one XCD. 512 blocks = 64/XCD = 4 mi-panels x 16 (ni,kz).
    const int b    = blockIdx.x;        // 0..511
    const int xcd  = b & 7;
    const int slot = b >> 3;            // 0..63
    const int mi_b = xcd * 4 + (slot & 3);   // 0..31
    const int nk   = slot >> 2;              // 0..15
    const int ni_b = nk & 3;                 // 0..3
    const int kz   = nk >> 2;                // 0..3

    const int m0 = mi_b * TM;
    const int n0 = ni_b * TN;
    const int kb = kz * (NC / SPLITK);

    // staging: wave w owns rows [w*32, w*32+32) of each array; 2 calls/array.
    const int srow = w * 32 + (lane >> 2);
    const int scol = (lane & 3) * 8;
    const unsigned short* gAh = Ahi + (size_t)(m0 + srow) * NC + kb + scol;
    const unsigned short* gAl = Alo + (size_t)(m0 + srow) * NC + kb + scol;
    const unsigned short* gBh = Whi + (size_t)(n0 + srow) * NC + kb + scol;
    const unsigned short* gBl = Wlo + (size_t)(n0 + srow) * NC + kb + scol;
    const int ld0 = (w * 32) * GK + lane * 8;   // linear dest; HW: lane0 base + lane*16B

    const int mw   = (w >> 1) * 64;
    const int nw   = (w & 1) * 64;
    const int sr   = lane & 15;
    const int quad = lane >> 4;
    const int rA = (mw + sr) * GK + quad * 8;
    const int rB = (nw + sr) * GK + quad * 8;

    f32x4 acc[4][4];
    #pragma unroll
    for (int i = 0; i < 4; ++i)
        #pragma unroll
        for (int j = 0; j < 4; ++j)
            acc[i][j] = (f32x4){0.f, 0.f, 0.f, 0.f};

    // 8 glds16 per wave per stage -> vmcnt +8 per STAGE
    #define STAGE(buf, kofs)                                          \
        {                                                             \
            const int ko = (kofs);                                    \
            glds16(gAh + ko,           &S[buf][0][ld0]);              \
            glds16(gAh + ko + 16 * NC, &S[buf][0][ld0 + 16 * GK]);    \
            glds16(gAl + ko,           &S[buf][1][ld0]);              \
            glds16(gAl + ko + 16 * NC, &S[buf][1][ld0 + 16 * GK]);    \
            glds16(gBh + ko,           &S[buf][2][ld0]);              \
            glds16(gBh + ko + 16 * NC, &S[buf][2][ld0 + 16 * GK]);    \
            glds16(gBl + ko,           &S[buf][3][ld0]);              \
            glds16(gBl + ko + 16 * NC, &S[buf][3][ld0 + 16 * GK]);    \
        }

    // one pipelined K-step; VMSTR = vmcnt immediate (8 steady-state, 0 last)
    #define KSTEP(CUR, VMSTR, DO_STAGE, NEXTK)                                 \
        {                                                                      \
            asm volatile("s_waitcnt vmcnt(" VMSTR ")" ::: "memory");           \
            __builtin_amdgcn_sched_barrier(0);                                 \
            __builtin_amdgcn_s_barrier();                                      \
            __builtin_amdgcn_sched_barrier(0);                                 \
            short8 afh[4], afl[4], bfh[4], bfl[4];                             \
            _Pragma("unroll")                                                  \
            for (int mi = 0; mi < 4; ++mi) {                                   \
                afh[mi] = *(const short8*)&S[CUR][0][rA + mi * 16 * GK];       \
                afl[mi] = *(const short8*)&S[CUR][1][rA + mi * 16 * GK];       \
            }                                                                  \
            _Pragma("unroll")                                                  \
            for (int ni = 0; ni < 4; ++ni) {                                   \
                bfh[ni] = *(const short8*)&S[CUR][2][rB + ni * 16 * GK];       \
                bfl[ni] = *(const short8*)&S[CUR][3][rB + ni * 16 * GK];       \
            }                                                                  \
            _Pragma("unroll")                                                  \
            for (int mi = 0; mi < 4; ++mi) {                                   \
                _Pragma("unroll")                                              \
                for (int ni = 0; ni < 4; ++ni) {                               \
                    acc[mi][ni] = __builtin_amdgcn_mfma_f32_16x16x32_bf16(     \
                        afh[mi], bfh[ni], acc[mi][ni], 0, 0, 0);               \
                    acc[mi][ni] = __builtin_amdgcn_mfma_f32_16x16x32_bf16(     \
                        afh[mi], bfl[ni], acc[mi][ni], 0, 0, 0);               \
                    acc[mi][ni] = __builtin_amdgcn_mfma_f32_16x16x32_bf16(     \
                        afl[mi], bfh[ni], acc[mi][ni], 0, 0, 0);               \
                }                                                              \
            }                                                                  \
            __builtin_amdgcn_sched_barrier(0);                                 \
            __builtin_amdgcn_s_barrier();                                      \
            __builtin_amdgcn_sched_barrier(0);                                 \
            if (DO_STAGE) STAGE(CUR, NEXTK);                                   \
        }

    // prologue: stages 0 and 1 in flight (16 DMA ops/wave outstanding)
    STAGE(0, 0);
    STAGE(1, GK);

    // steady state: buffer overwritten only after the barrier that ends its
    // readers; loads get a full step to land before their vmcnt(8) wait.
    #pragma unroll 2
    for (int s = 0; s < NST - 2; ++s)
        KSTEP((s & 1), "8", true, (s + 2) * GK);
    // peeled tail: s = NST-2 (cur=0), s = NST-1 (cur=1, full drain)
    KSTEP(0, "8", false, 0);
    KSTEP(1, "0", false, 0);

    // epilogue: C/D layout col = lane&15, row = quad*4 + reg  [m89/m91]
    float* Dz = Dp + (size_t)kz * BATCH * NL;
    #pragma unroll
    for (int mi = 0; mi < 4; ++mi) {
        #pragma unroll
        for (int ni = 0; ni < 4; ++ni) {
            const int col = n0 + nw + ni * 16 + sr;
            #pragma unroll
            for (int r = 0; r < 4; ++r) {
                const int row = m0 + mw + mi * 16 + quad * 4 + r;
                Dz[(size_t)row * NL + col] = acc[mi][ni][r];
            }
        }
    }
}

// ------ 50-step recurrence + selection: 64 lanes per row, 8 cols/lane -------
template<int SK>
__global__ __launch_bounds__(256)
void iterate_select(const float* __restrict__ Dp,
                    float* __restrict__ a_out,
                    float* __restrict__ sel_out, float* __restrict__ conf_out) {
    const int lane = threadIdx.x & 63;
    const int wave = threadIdx.x >> 6;
    const int row  = blockIdx.x * 4 + wave;

    float d[8];
    {
        float4 v[SK][2];
        #pragma unroll
        for (int s = 0; s < SK; ++s) {
            const float4* ps = (const float4*)(Dp + (size_t)s * BATCH * NL
                                               + (size_t)row * NL + lane * 8);
            v[s][0] = ps[0];
            v[s][1] = ps[1];
        }
        d[0] = v[0][0].x; d[1] = v[0][0].y; d[2] = v[0][0].z; d[3] = v[0][0].w;
        d[4] = v[0][1].x; d[5] = v[0][1].y; d[6] = v[0][1].z; d[7] = v[0][1].w;
        #pragma unroll
        for (int s = 1; s < SK; ++s) {
            d[0] += v[s][0].x; d[1] += v[s][0].y; d[2] += v[s][0].z; d[3] += v[s][0].w;
            d[4] += v[s][1].x; d[5] += v[s][1].y; d[6] += v[s][1].z; d[7] += v[s][1].w;
        }
    }

    float a[8];
    #pragma unroll
    for (int j = 0; j < 8; ++j) a[j] = 0.f;

    const float K1 = 1.0f + KAPPA_C;

    for (int t = 0; t < TSTEPS; ++t) {
        #pragma unroll
        for (int j = 0; j < 8; ++j) a[j] = fmaf(GAMMA_C, a[j], d[j]);

        float t4a = a[0] + a[4], t4b = a[1] + a[5], t4c = a[2] + a[6], t4d = a[3] + a[7];
        float t2a = t4a + t4c, t2b = t4b + t4d;
        const float S = wave_sum_bcast(t2a + t2b);

        const float h = -KAPPA_C * S;
        #pragma unroll
        for (int j = 0; j < 8; ++j) {
            const float v = fmaf(K1, a[j], h);
            a[j] = v > 0.f ? v : 0.f;
        }
    }

    // ---- epilogue (runs once): peak, sum, confidence, first-index argmax ----
    float m4a = fmaxf(a[0], a[4]), m4b = fmaxf(a[1], a[5]);
    float m4c = fmaxf(a[2], a[6]), m4d = fmaxf(a[3], a[7]);
    float peak = fmaxf(fmaxf(m4a, m4b), fmaxf(m4c, m4d));
    float s4a = a[0] + a[4], s4b = a[1] + a[5], s4c = a[2] + a[6], s4d = a[3] + a[7];
    float ssum = wave_sum_bcast((s4a + s4b) + (s4c + s4d));

    #pragma unroll
    for (int m = 1; m < 64; m <<= 1)
        peak = fmaxf(peak, __shfl_xor(peak, m, 64));

    const float mean = ssum * (1.0f / (float)NL);
    const float conf = peak / fmaxf(mean, FLOOR_C);

    int idx = 0x7fffffff;
    #pragma unroll
    for (int j = 0; j < 8; ++j)
        if (a[j] == peak) idx = min(idx, lane * 8 + j);
    #pragma unroll
    for (int m = 1; m < 64; m <<= 1)
        idx = min(idx, __shfl_xor(idx, m, 64));

    float4* ar = (float4*)(a_out + (size_t)row * NL + lane * 8);
    float4 o0, o1;
    o0.x = a[0]; o0.y = a[1]; o0.z = a[2]; o0.w = a[3];
    o1.x = a[4]; o1.y = a[5]; o1.z = a[6]; o1.w = a[7];
    ar[0] = o0; ar[1] = o1;

    if (lane == 0) {
        if (sel_out)  sel_out[row]  = (float)idx;
        if (conf_out) conf_out[row] = conf;
    }
}

extern "C" void kernel_launch(void* const* d_in, const int* in_sizes, int n_in,
                              void* d_out, int out_size, void* d_ws, size_t ws_size,
                              hipStream_t stream) {
    const float* c_lex = (const float*)d_in[0];
    const float* W     = (const float*)d_in[1];
    // d_in[2] = a0 (zeros at every reset; recurrence inits a=0 directly)

    // workspace: 4 D-partials (33.6 MB) + Whi/Wlo (4.2 MB) + Ahi/Alo (33.6 MB)
    float* D = (float*)d_ws;
    unsigned short* Whi = (unsigned short*)(D + (size_t)SPLITK * BATCH * NL);
    unsigned short* Wlo = Whi + (size_t)NL * NC;
    unsigned short* Ahi = Wlo + (size_t)NL * NC;
    unsigned short* Alo = Ahi + (size_t)BATCH * NC;

    float* a_out = (float*)d_out;
    float* sel   = nullptr;
    float* conf  = nullptr;
    const int base = BATCH * NL;
    if (out_size >= base + 2 * BATCH) {        // (a, selected, confidence)
        sel  = a_out + base;
        conf = a_out + base + BATCH;
    } else if (out_size >= base + BATCH) {     // (a, confidence)
        conf = a_out + base;
    }

    // 1) W and A fp32 -> bf16 hi/lo (one streaming pass, ~42 MB)
    convert_hilo<<<dim3(W_BLOCKS + A_BLOCKS), 256, 0, stream>>>(
        W, c_lex, Whi, Wlo, Ahi, Alo);

    // 2) MFMA GEMM, counted-vmcnt pipeline, splitK=4, XCD-swizzled 512 blocks
    gemm_bf16x2<<<dim3(512), 256, 0, stream>>>(Ahi, Alo, Whi, Wlo, D);

    // 3) recurrence + selection: 1 row/wave, 4 waves/SIMD, DPP row-sum
    iterate_select<SPLITK><<<dim3(BATCH / 4), 256, 0, stream>>>(D, a_out, sel, conf);
}